// Round 1
// baseline (311.355 us; speedup 1.0000x reference)
//
#include <hip/hip_runtime.h>

// AdvectionLayer: bilinear warp of image [B=8,C=4,H=1024,W=1024] by flow [B,2,H,W].
//
// R1: planar gather, TA/line-fill limited, 274 us (kernel).
// R2: fp32 channel-interleaved ws, 4 float4 gathers -> 145 us, line-fill limited.
// R3: fp16 channel-interleaved ws + 32x8 tiles; harness 309.4 us. rocprof showed
//     both kernels < 77 us each -> ~155 us of the harness time is workspace
//     poison fills (2x 78 us @ 512 MiB); kernel portion ~150 us.
// R4 (this): single fused kernel, no workspace. Stage (tile+halo) image region
//     into LDS as fp16 channel-interleaved (8 B/px), bilinear-gather from LDS.
//     Kills the interleave pass (192 MiB HBM round trip) and converts scattered
//     global 16B gathers into LDS reads. Tail pixels whose taps fall outside
//     the halo (|disp| > ~15.5 px, ~2e-4 of pixels) take a rare per-lane
//     planar fp32 global fallback.

#define BB 8
#define CC 4
#define HH 1024
#define WW 1024
#define HW (HH * WW)

#define TX 64     // tile width  (output px)
#define TY 16     // tile height (output px)
#define HALO 16   // 4-sigma of N(0,4) flow
#define RW 98     // staged cols: x0-16 .. x0+81 ; gather uses rx<=96, rx+1<=97
#define RH 49     // staged rows: y0-16 .. y0+32 ; gather uses ry<=47, ry+1<=48

typedef _Float16 h4 __attribute__((ext_vector_type(4)));  // one px, 4 ch, 8 B
typedef _Float16 h8 __attribute__((ext_vector_type(8)));  // px pair, 16 B

__global__ __launch_bounds__(256) void advect_fused_kernel(
    const float* __restrict__ image,
    const float* __restrict__ flow,
    float* __restrict__ out)
{
    __shared__ h4 lds[RH][RW];   // 49*98*8 = 38416 B -> 4 blocks/CU

    const int tid = threadIdx.x;
    const int x0 = blockIdx.x * TX;
    const int y0 = blockIdx.y * TY;
    const int b  = blockIdx.z;

    const float* img = image + (size_t)b * CC * HW;

    // ---- stage RH x RW halo region as 49 column-pairs per row (coalesced) ----
    // Border cells are clamp-duplicated; any cell a gather can actually read
    // corresponds to a genuine in-range source pixel (xl,yl are pre-clamped),
    // so the duplication never affects results.
    for (int e = tid; e < RH * (RW / 2); e += 256) {
        const int r  = e / (RW / 2);
        const int pc = e - r * (RW / 2);
        const int gy  = min(max(y0 - HALO + r, 0), HH - 1);
        const int gxb = min(max(x0 - HALO + 2 * pc, 0), WW - 2);
        const float* p = img + (size_t)gy * WW + gxb;
        float2 c0, c1, c2, c3;
        __builtin_memcpy(&c0, p,          8);
        __builtin_memcpy(&c1, p + HW,     8);
        __builtin_memcpy(&c2, p + 2 * HW, 8);
        __builtin_memcpy(&c3, p + 3 * HW, 8);
        h8 pr;
        pr[0] = (_Float16)c0.x; pr[1] = (_Float16)c1.x;
        pr[2] = (_Float16)c2.x; pr[3] = (_Float16)c3.x;
        pr[4] = (_Float16)c0.y; pr[5] = (_Float16)c1.y;
        pr[6] = (_Float16)c2.y; pr[7] = (_Float16)c3.y;
        *(h8*)&lds[r][2 * pc] = pr;   // 16B-aligned ds_write_b128
    }
    __syncthreads();

    // ---- gather: each wave owns one 64-wide row, 4 rows per wave ----
    const int tx = tid & 63;
    const int x  = x0 + tx;
    const int yb = y0 + ((tid >> 6) << 2);

    const float sxs = (float)WW / (float)(WW - 1);
    const float sys = (float)HH / (float)(HH - 1);

    const float* flb = flow + (size_t)b * 2 * HW;
    float* outb = out + (size_t)b * CC * HW;

#pragma unroll
    for (int k = 0; k < 4; ++k) {
        const int y = yb + k;
        const float* fl = flb + (size_t)y * WW + x;
        const float fx = fl[0];
        const float fy = fl[HW];

        float ix = ((float)x + fx) * sxs - 0.5f;
        float iy = ((float)y + fy) * sys - 0.5f;
        ix = fminf(fmaxf(ix, 0.0f), (float)(WW - 1));
        iy = fminf(fmaxf(iy, 0.0f), (float)(HH - 1));
        const int xl = min((int)ix, WW - 2);
        const int yl = min((int)iy, HH - 2);
        const float wx = ix - (float)xl;
        const float wy = iy - (float)yl;
        const float u0 = 1.0f - wx;
        const float v0 = 1.0f - wy;

        const int rx = xl - x0 + HALO;
        const int ry = yl - y0 + HALO;

        float o0, o1, o2, o3;
        if ((unsigned)rx <= (unsigned)(RW - 2) && (unsigned)ry <= (unsigned)(RH - 2)) {
            const h4 a00 = lds[ry][rx];
            const h4 a01 = lds[ry][rx + 1];
            const h4 a10 = lds[ry + 1][rx];
            const h4 a11 = lds[ry + 1][rx + 1];
            o0 = v0 * (u0 * (float)a00[0] + wx * (float)a01[0])
               + wy * (u0 * (float)a10[0] + wx * (float)a11[0]);
            o1 = v0 * (u0 * (float)a00[1] + wx * (float)a01[1])
               + wy * (u0 * (float)a10[1] + wx * (float)a11[1]);
            o2 = v0 * (u0 * (float)a00[2] + wx * (float)a01[2])
               + wy * (u0 * (float)a10[2] + wx * (float)a11[2]);
            o3 = v0 * (u0 * (float)a00[3] + wx * (float)a01[3])
               + wy * (u0 * (float)a10[3] + wx * (float)a11[3]);
        } else {
            // rare Gaussian-tail fallback: planar fp32 gather
            const size_t o00 = (size_t)yl * WW + xl;
            float2 t, bt;
            const float* p0 = img + o00;
            __builtin_memcpy(&t,  p0,      8);
            __builtin_memcpy(&bt, p0 + WW, 8);
            o0 = v0 * (u0 * t.x + wx * t.y) + wy * (u0 * bt.x + wx * bt.y);
            p0 += HW;
            __builtin_memcpy(&t,  p0,      8);
            __builtin_memcpy(&bt, p0 + WW, 8);
            o1 = v0 * (u0 * t.x + wx * t.y) + wy * (u0 * bt.x + wx * bt.y);
            p0 += HW;
            __builtin_memcpy(&t,  p0,      8);
            __builtin_memcpy(&bt, p0 + WW, 8);
            o2 = v0 * (u0 * t.x + wx * t.y) + wy * (u0 * bt.x + wx * bt.y);
            p0 += HW;
            __builtin_memcpy(&t,  p0,      8);
            __builtin_memcpy(&bt, p0 + WW, 8);
            o3 = v0 * (u0 * t.x + wx * t.y) + wy * (u0 * bt.x + wx * bt.y);
        }

        const size_t op = (size_t)y * WW + x;
        outb[op]            = o0;
        outb[HW + op]       = o1;
        outb[2 * (size_t)HW + op] = o2;
        outb[3 * (size_t)HW + op] = o3;
    }
}

extern "C" void kernel_launch(void* const* d_in, const int* in_sizes, int n_in,
                              void* d_out, int out_size, void* d_ws, size_t ws_size,
                              hipStream_t stream) {
    const float* image = (const float*)d_in[0];
    const float* flow  = (const float*)d_in[1];
    float* out = (float*)d_out;

    dim3 grid(WW / TX, HH / TY, BB);
    advect_fused_kernel<<<grid, 256, 0, stream>>>(image, flow, out);
}

// Round 2
// 292.869 us; speedup vs baseline: 1.0631x; 1.0631x over previous
//
#include <hip/hip_runtime.h>

// AdvectionLayer: bilinear warp of image [B=8,C=4,H=1024,W=1024] by flow [B,2,H,W].
//
// R1: planar gather, TA/line-fill limited, 274 us (kernel).
// R2: fp32 channel-interleaved ws, 4 float4 gathers -> 145 us, line-fill limited.
// R3: fp16 channel-interleaved ws + 32x8 tiles; ~150 us kernel total (two kernels).
// R4: fused single kernel, LDS fp16-interleaved tile+halo staging, 135 us.
//     rocprof: FETCH 181 MiB + WRITE 128 MiB = near-minimal traffic, but only
//     2.4 TB/s, VALUBusy 22%, Occupancy 41% (cap 50%: 4 blk/CU x 4 waves).
//     => latency/occupancy-bound, not traffic-bound.
// R5 (this): same 64x16 tile / 38.4 KB LDS (4 blk/CU) but 512-thread blocks
//     -> occupancy cap 32 waves/CU (100%). launch_bounds(512,8) caps VGPR at 64.
//     2 px/thread gather, 5-iter unrolled staging for ILP. Non-temporal out
//     stores + flow loads (single-touch data) to keep L2 for staging re-reads.

#define BB 8
#define CC 4
#define HH 1024
#define WW 1024
#define HW (HH * WW)

#define TX 64     // tile width  (output px)
#define TY 16     // tile height (output px)
#define HALO 16   // 4-sigma of N(0,4) flow
#define RW 98     // staged cols: x0-16 .. x0+81 ; gather uses rx<=96, rx+1<=97
#define RH 49     // staged rows: y0-16 .. y0+32 ; gather uses ry<=47, ry+1<=48
#define NENT (RH * (RW / 2))   // 2401 column-pair entries

typedef _Float16 h4 __attribute__((ext_vector_type(4)));  // one px, 4 ch, 8 B
typedef _Float16 h8 __attribute__((ext_vector_type(8)));  // px pair, 16 B

__global__ __launch_bounds__(512, 8) void advect_fused_kernel(
    const float* __restrict__ image,
    const float* __restrict__ flow,
    float* __restrict__ out)
{
    __shared__ h4 lds[RH][RW];   // 49*98*8 = 38416 B -> 4 blocks/CU

    const int tid = threadIdx.x;
    const int x0 = blockIdx.x * TX;
    const int y0 = blockIdx.y * TY;
    const int b  = blockIdx.z;

    const float* img = image + (size_t)b * CC * HW;

    // ---- stage RH x RW halo region as 49 column-pairs per row (coalesced) ----
    // Border cells are clamp-duplicated; any cell a gather can actually read
    // corresponds to a genuine in-range source pixel (xl,yl are pre-clamped),
    // so the duplication never affects results. Iterations 0..3 are
    // compile-time unconditional (512*4 = 2048 < 2401); only iter 4 is guarded.
#pragma unroll
    for (int i = 0; i < 5; ++i) {
        const int e = i * 512 + tid;
        if (e < NENT) {
            const int r  = e / (RW / 2);
            const int pc = e - r * (RW / 2);
            const int gy  = min(max(y0 - HALO + r, 0), HH - 1);
            const int gxb = min(max(x0 - HALO + 2 * pc, 0), WW - 2);
            const float* p = img + (size_t)gy * WW + gxb;
            float2 c0, c1, c2, c3;
            __builtin_memcpy(&c0, p,          8);
            __builtin_memcpy(&c1, p + HW,     8);
            __builtin_memcpy(&c2, p + 2 * HW, 8);
            __builtin_memcpy(&c3, p + 3 * HW, 8);
            h8 pr;
            pr[0] = (_Float16)c0.x; pr[1] = (_Float16)c1.x;
            pr[2] = (_Float16)c2.x; pr[3] = (_Float16)c3.x;
            pr[4] = (_Float16)c0.y; pr[5] = (_Float16)c1.y;
            pr[6] = (_Float16)c2.y; pr[7] = (_Float16)c3.y;
            *(h8*)&lds[r][2 * pc] = pr;   // 16B-aligned ds_write_b128
        }
    }
    __syncthreads();

    // ---- gather: 8 waves, each owns a 64-wide row pair {ty, ty+8} ----
    const int tx  = tid & 63;
    const int x   = x0 + tx;
    const int ty0 = tid >> 6;          // 0..7

    const float sxs = (float)WW / (float)(WW - 1);
    const float sys = (float)HH / (float)(HH - 1);

    const float* flb = flow + (size_t)b * 2 * HW;
    float* outb = out + (size_t)b * CC * HW;

#pragma unroll
    for (int k = 0; k < 2; ++k) {
        const int y = y0 + ty0 + (k << 3);
        const float* fl = flb + (size_t)y * WW + x;
        const float fx = __builtin_nontemporal_load(fl);
        const float fy = __builtin_nontemporal_load(fl + HW);

        float ix = ((float)x + fx) * sxs - 0.5f;
        float iy = ((float)y + fy) * sys - 0.5f;
        ix = fminf(fmaxf(ix, 0.0f), (float)(WW - 1));
        iy = fminf(fmaxf(iy, 0.0f), (float)(HH - 1));
        const int xl = min((int)ix, WW - 2);
        const int yl = min((int)iy, HH - 2);
        const float wx = ix - (float)xl;
        const float wy = iy - (float)yl;
        const float u0 = 1.0f - wx;
        const float v0 = 1.0f - wy;

        const int rx = xl - x0 + HALO;
        const int ry = yl - y0 + HALO;

        float o0, o1, o2, o3;
        if ((unsigned)rx <= (unsigned)(RW - 2) && (unsigned)ry <= (unsigned)(RH - 2)) {
            const h4 a00 = lds[ry][rx];
            const h4 a01 = lds[ry][rx + 1];
            const h4 a10 = lds[ry + 1][rx];
            const h4 a11 = lds[ry + 1][rx + 1];
            o0 = v0 * (u0 * (float)a00[0] + wx * (float)a01[0])
               + wy * (u0 * (float)a10[0] + wx * (float)a11[0]);
            o1 = v0 * (u0 * (float)a00[1] + wx * (float)a01[1])
               + wy * (u0 * (float)a10[1] + wx * (float)a11[1]);
            o2 = v0 * (u0 * (float)a00[2] + wx * (float)a01[2])
               + wy * (u0 * (float)a10[2] + wx * (float)a11[2]);
            o3 = v0 * (u0 * (float)a00[3] + wx * (float)a01[3])
               + wy * (u0 * (float)a10[3] + wx * (float)a11[3]);
        } else {
            // rare Gaussian-tail fallback (~2e-4 of pixels): planar fp32 gather
            const size_t o00 = (size_t)yl * WW + xl;
            float2 t, bt;
            const float* p0 = img + o00;
            __builtin_memcpy(&t,  p0,      8);
            __builtin_memcpy(&bt, p0 + WW, 8);
            o0 = v0 * (u0 * t.x + wx * t.y) + wy * (u0 * bt.x + wx * bt.y);
            p0 += HW;
            __builtin_memcpy(&t,  p0,      8);
            __builtin_memcpy(&bt, p0 + WW, 8);
            o1 = v0 * (u0 * t.x + wx * t.y) + wy * (u0 * bt.x + wx * bt.y);
            p0 += HW;
            __builtin_memcpy(&t,  p0,      8);
            __builtin_memcpy(&bt, p0 + WW, 8);
            o2 = v0 * (u0 * t.x + wx * t.y) + wy * (u0 * bt.x + wx * bt.y);
            p0 += HW;
            __builtin_memcpy(&t,  p0,      8);
            __builtin_memcpy(&bt, p0 + WW, 8);
            o3 = v0 * (u0 * t.x + wx * t.y) + wy * (u0 * bt.x + wx * bt.y);
        }

        const size_t op = (size_t)y * WW + x;
        __builtin_nontemporal_store(o0, &outb[op]);
        __builtin_nontemporal_store(o1, &outb[HW + op]);
        __builtin_nontemporal_store(o2, &outb[2 * (size_t)HW + op]);
        __builtin_nontemporal_store(o3, &outb[3 * (size_t)HW + op]);
    }
}

extern "C" void kernel_launch(void* const* d_in, const int* in_sizes, int n_in,
                              void* d_out, int out_size, void* d_ws, size_t ws_size,
                              hipStream_t stream) {
    const float* image = (const float*)d_in[0];
    const float* flow  = (const float*)d_in[1];
    float* out = (float*)d_out;

    dim3 grid(WW / TX, HH / TY, BB);
    advect_fused_kernel<<<grid, 512, 0, stream>>>(image, flow, out);
}

// Round 3
// 273.299 us; speedup vs baseline: 1.1392x; 1.0716x over previous
//
#include <hip/hip_runtime.h>

// AdvectionLayer: bilinear warp of image [B=8,C=4,H=1024,W=1024] by flow [B,2,H,W].
//
// R1: planar gather, 274 us. R2: fp32 interleaved ws, 145 us. R3: fp16 ws, ~150 us.
// R4: fused LDS fp16 tile+halo, 135 us; traffic near-minimal, occupancy 41%.
// R5: 512-thr blocks -> occupancy 77%, but only 114 us / 2.6 TB/s. Doubling TLP
//     at constant traffic gained 16% => throughput wall below HBM: the halo-
//     amplified staging stream (4.69 staged px / out px = 75 B/out-px ~ 630 MB
//     through L2/L3) is the remaining wall. VALU 25%, conflicts 5%, HBM 33%.
// R6 (this): cut staged bytes/out-px 1.95x. 64x32 tile (4 px/thread), halo
//     x:-12/+11.5 y:-11/+12.5 (~2.9 sigma) -> staged 88x56, amp 2.41x,
//     LDS 39.4 KB keeps 4 blk/CU = 32 waves/CU cap. float4 staging loads
//     (aligned window), flow prefetched to regs before staging so gather has
//     no global dependency. Fallback rate rises to ~0.9% (exec-masked exact
//     planar path) - deliberate trade for the traffic cut.

#define BB 8
#define CC 4
#define HH 1024
#define WW 1024
#define HW (HH * WW)

#define TX 64     // tile width  (output px)
#define TY 32     // tile height (output px)
#define HXL 12    // left x halo; window [x0-12, x0+76) keeps 16B alignment
#define HYT 11    // top y halo;  window [y0-11, y0+45)
#define RW 88     // staged cols; valid xl: rx in [0, 86]
#define RH 56     // staged rows; valid yl: ry in [0, 54]
#define NQ (RW / 4)        // 22 float4-quads per staged row
#define NENT (RH * NQ)     // 1232 staging entries

typedef _Float16 h4 __attribute__((ext_vector_type(4)));  // one px, 4 ch, 8 B
typedef _Float16 h8 __attribute__((ext_vector_type(8)));  // px pair, 16 B

__global__ __launch_bounds__(512, 8) void advect_fused_kernel(
    const float* __restrict__ image,
    const float* __restrict__ flow,
    float* __restrict__ out)
{
    __shared__ h4 lds[RH][RW];   // 56*88*8 = 39424 B -> 4 blocks/CU

    const int tid = threadIdx.x;
    const int x0 = blockIdx.x * TX;
    const int y0 = blockIdx.y * TY;
    const int b  = blockIdx.z;

    const float* img = image + (size_t)b * CC * HW;
    const float* flb = flow + (size_t)b * 2 * HW;

    const int tx  = tid & 63;
    const int x   = x0 + tx;
    const int ty0 = tid >> 6;          // 0..7; rows ty0 + 8k, k=0..3

    // ---- prefetch flow for all 4 output px before staging (latency hides
    //      under the staging loads + barrier) ----
    float pfx[4], pfy[4];
#pragma unroll
    for (int k = 0; k < 4; ++k) {
        const float* fl = flb + (size_t)(y0 + ty0 + (k << 3)) * WW + x;
        pfx[k] = __builtin_nontemporal_load(fl);
        pfy[k] = __builtin_nontemporal_load(fl + HW);
    }

    // ---- stage RH x RW halo region, 4-px quads, aligned float4 loads ----
    // Quad base clamped to [0, W-4] (preserves 16B alignment). Clamp-mangled
    // border cells are never read by the gather (xl,yl are pre-clamped into
    // the genuine image range, and tail px outside the halo take the exact
    // global fallback). Iterations 0-1 unconditional (1024 < 1232), 2 guarded.
#pragma unroll
    for (int i = 0; i < 3; ++i) {
        const int e = i * 512 + tid;
        if (e < NENT) {
            const int r = e / NQ;
            const int q = e - r * NQ;
            const int gy = min(max(y0 - HYT + r, 0), HH - 1);
            const int gx = min(max(x0 - HXL + 4 * q, 0), WW - 4);
            const float* p = img + (size_t)gy * WW + gx;
            const float4 c0 = *reinterpret_cast<const float4*>(p);
            const float4 c1 = *reinterpret_cast<const float4*>(p + HW);
            const float4 c2 = *reinterpret_cast<const float4*>(p + 2 * HW);
            const float4 c3 = *reinterpret_cast<const float4*>(p + 3 * HW);
            h8 lo, hi;
            lo[0] = (_Float16)c0.x; lo[1] = (_Float16)c1.x;
            lo[2] = (_Float16)c2.x; lo[3] = (_Float16)c3.x;
            lo[4] = (_Float16)c0.y; lo[5] = (_Float16)c1.y;
            lo[6] = (_Float16)c2.y; lo[7] = (_Float16)c3.y;
            hi[0] = (_Float16)c0.z; hi[1] = (_Float16)c1.z;
            hi[2] = (_Float16)c2.z; hi[3] = (_Float16)c3.z;
            hi[4] = (_Float16)c0.w; hi[5] = (_Float16)c1.w;
            hi[6] = (_Float16)c2.w; hi[7] = (_Float16)c3.w;
            *(h8*)&lds[r][4 * q]     = lo;
            *(h8*)&lds[r][4 * q + 2] = hi;
        }
    }
    __syncthreads();

    const float sxs = (float)WW / (float)(WW - 1);
    const float sys = (float)HH / (float)(HH - 1);

    float* outb = out + (size_t)b * CC * HW;

#pragma unroll
    for (int k = 0; k < 4; ++k) {
        const int y = y0 + ty0 + (k << 3);
        const float fx = pfx[k];
        const float fy = pfy[k];

        float ix = ((float)x + fx) * sxs - 0.5f;
        float iy = ((float)y + fy) * sys - 0.5f;
        ix = fminf(fmaxf(ix, 0.0f), (float)(WW - 1));
        iy = fminf(fmaxf(iy, 0.0f), (float)(HH - 1));
        const int xl = min((int)ix, WW - 2);
        const int yl = min((int)iy, HH - 2);
        const float wx = ix - (float)xl;
        const float wy = iy - (float)yl;
        const float u0 = 1.0f - wx;
        const float v0 = 1.0f - wy;

        const int rx = xl - x0 + HXL;
        const int ry = yl - y0 + HYT;

        float o0, o1, o2, o3;
        if ((unsigned)rx <= (unsigned)(RW - 2) && (unsigned)ry <= (unsigned)(RH - 2)) {
            const h4 a00 = lds[ry][rx];
            const h4 a01 = lds[ry][rx + 1];
            const h4 a10 = lds[ry + 1][rx];
            const h4 a11 = lds[ry + 1][rx + 1];
            o0 = v0 * (u0 * (float)a00[0] + wx * (float)a01[0])
               + wy * (u0 * (float)a10[0] + wx * (float)a11[0]);
            o1 = v0 * (u0 * (float)a00[1] + wx * (float)a01[1])
               + wy * (u0 * (float)a10[1] + wx * (float)a11[1]);
            o2 = v0 * (u0 * (float)a00[2] + wx * (float)a01[2])
               + wy * (u0 * (float)a10[2] + wx * (float)a11[2]);
            o3 = v0 * (u0 * (float)a00[3] + wx * (float)a01[3])
               + wy * (u0 * (float)a10[3] + wx * (float)a11[3]);
        } else {
            // Gaussian-tail fallback (~0.9% of px): exact planar fp32 gather
            const size_t o00 = (size_t)yl * WW + xl;
            float2 t, bt;
            const float* p0 = img + o00;
            __builtin_memcpy(&t,  p0,      8);
            __builtin_memcpy(&bt, p0 + WW, 8);
            o0 = v0 * (u0 * t.x + wx * t.y) + wy * (u0 * bt.x + wx * bt.y);
            p0 += HW;
            __builtin_memcpy(&t,  p0,      8);
            __builtin_memcpy(&bt, p0 + WW, 8);
            o1 = v0 * (u0 * t.x + wx * t.y) + wy * (u0 * bt.x + wx * bt.y);
            p0 += HW;
            __builtin_memcpy(&t,  p0,      8);
            __builtin_memcpy(&bt, p0 + WW, 8);
            o2 = v0 * (u0 * t.x + wx * t.y) + wy * (u0 * bt.x + wx * bt.y);
            p0 += HW;
            __builtin_memcpy(&t,  p0,      8);
            __builtin_memcpy(&bt, p0 + WW, 8);
            o3 = v0 * (u0 * t.x + wx * t.y) + wy * (u0 * bt.x + wx * bt.y);
        }

        const size_t op = (size_t)y * WW + x;
        __builtin_nontemporal_store(o0, &outb[op]);
        __builtin_nontemporal_store(o1, &outb[HW + op]);
        __builtin_nontemporal_store(o2, &outb[2 * (size_t)HW + op]);
        __builtin_nontemporal_store(o3, &outb[3 * (size_t)HW + op]);
    }
}

extern "C" void kernel_launch(void* const* d_in, const int* in_sizes, int n_in,
                              void* d_out, int out_size, void* d_ws, size_t ws_size,
                              hipStream_t stream) {
    const float* image = (const float*)d_in[0];
    const float* flow  = (const float*)d_in[1];
    float* out = (float*)d_out;

    dim3 grid(WW / TX, HH / TY, BB);
    advect_fused_kernel<<<grid, 512, 0, stream>>>(image, flow, out);
}